// Round 1
// baseline (3602.827 us; speedup 1.0000x reference)
//
#include <hip/hip_runtime.h>

#define BATCH 2048
#define SEQT  2000
#define H1    51

__device__ __forceinline__ float rl(float v, int lane) {
    return __int_as_float(__builtin_amdgcn_readlane(__float_as_int(v), lane));
}
__device__ __forceinline__ float sigf(float x) {
    return 1.f / (1.f + __expf(-x));
}
__device__ __forceinline__ float tanhfast(float x) {
    // 1 - 2/(e^{2x}+1); saturates correctly at +-1 for large |x|
    return 1.f - 2.f / (__expf(2.f * x) + 1.f);
}

__global__ __launch_bounds__(64, 2)
void lstm_seq_kernel(const float* __restrict__ input,
                     const float* __restrict__ W_ih1,
                     const float* __restrict__ W_hh1,
                     const float* __restrict__ b_ih1,
                     const float* __restrict__ b_hh1,
                     const float* __restrict__ W_ih3,
                     const float* __restrict__ W_hh3,
                     const float* __restrict__ b_ih3,
                     const float* __restrict__ b_hh3,
                     float* __restrict__ out) {
    const int b = blockIdx.x;      // one batch row per wave
    const int j = threadIdx.x;     // lane j owns hidden unit j (j<51)
    const bool act = (j < H1);
    const int js = act ? j : 0;    // safe index for inactive lanes

    // ---- load per-unit weights into registers (once) ----
    // lane j holds W_hh1 rows {j, 51+j, 102+j, 153+j} = (i,f,g,o) of unit j
    float w[4][H1];
    float wihx[4], bias[4], wih3j[4];
#pragma unroll
    for (int g = 0; g < 4; ++g) {
        const int row = g * H1 + js;
        const float* wrow = W_hh1 + (size_t)row * H1;
#pragma unroll
        for (int k = 0; k < H1; ++k)
            w[g][k] = act ? wrow[k] : 0.f;
        wihx[g]  = act ? W_ih1[row] : 0.f;
        bias[g]  = act ? (b_ih1[row] + b_hh1[row]) : 0.f;
        wih3j[g] = act ? W_ih3[g * H1 + j] : 0.f;   // inactive lanes contribute 0 to reduce
    }
    // tiny lstm3 scalars (uniform on all lanes)
    float whh3[4], b3[4];
#pragma unroll
    for (int g = 0; g < 4; ++g) {
        whh3[g] = W_hh3[g];
        b3[g]   = b_ih3[g] + b_hh3[g];
    }

    float h1v = 0.f, c1v = 0.f;   // state of unit j (distributed across lanes)
    float h3 = 0.f, c3 = 0.f;     // uniform scalar state (all lanes compute it)

    const size_t rowbase = (size_t)b * SEQT;

    for (int t0 = 0; t0 < SEQT; t0 += 64) {
        // coalesced fetch of 64 timesteps of x into one register
        const int idx = t0 + j;
        float xv = (idx < SEQT) ? input[rowbase + idx] : 0.f;
        const int tend = (SEQT - t0 < 64) ? (SEQT - t0) : 64;

        for (int tt = 0; tt < tend; ++tt) {
            const float xt = rl(xv, tt);

            // ---- LSTM1 gates: bias + x*W_ih + h1 @ W_hh^T (unit j's 4 rows) ----
            float ai = fmaf(xt, wihx[0], bias[0]);
            float af = fmaf(xt, wihx[1], bias[1]);
            float ag = fmaf(xt, wihx[2], bias[2]);
            float ao = fmaf(xt, wihx[3], bias[3]);
#pragma unroll
            for (int k = 0; k < H1; ++k) {
                const float hk = rl(h1v, k);   // broadcast h1[k] from lane k
                ai = fmaf(hk, w[0][k], ai);
                af = fmaf(hk, w[1][k], af);
                ag = fmaf(hk, w[2][k], ag);
                ao = fmaf(hk, w[3][k], ao);
            }
            c1v = sigf(af) * c1v + sigf(ai) * tanhfast(ag);
            h1v = sigf(ao) * tanhfast(c1v);

            // ---- LSTM3: gates = W_ih3 @ c1 + b + W_hh3*h3 (H3 = 1) ----
            float p0 = c1v * wih3j[0];
            float p1 = c1v * wih3j[1];
            float p2 = c1v * wih3j[2];
            float p3 = c1v * wih3j[3];
#pragma unroll
            for (int m = 1; m < 64; m <<= 1) {   // full butterfly -> sum on all lanes
                p0 += __shfl_xor(p0, m);
                p1 += __shfl_xor(p1, m);
                p2 += __shfl_xor(p2, m);
                p3 += __shfl_xor(p3, m);
            }
            const float gi = fmaf(whh3[0], h3, p0) + b3[0];
            const float gf = fmaf(whh3[1], h3, p1) + b3[1];
            const float gg = fmaf(whh3[2], h3, p2) + b3[2];
            const float go = fmaf(whh3[3], h3, p3) + b3[3];
            c3 = sigf(gf) * c3 + sigf(gi) * tanhfast(gg);
            h3 = sigf(go) * tanhfast(c3);

            if (j == 0) out[rowbase + t0 + tt] = c3;
        }
    }
}

extern "C" void kernel_launch(void* const* d_in, const int* in_sizes, int n_in,
                              void* d_out, int out_size, void* d_ws, size_t ws_size,
                              hipStream_t stream) {
    const float* input = (const float*)d_in[0];
    const float* W_ih1 = (const float*)d_in[1];
    const float* W_hh1 = (const float*)d_in[2];
    const float* b_ih1 = (const float*)d_in[3];
    const float* b_hh1 = (const float*)d_in[4];
    const float* W_ih3 = (const float*)d_in[5];
    const float* W_hh3 = (const float*)d_in[6];
    const float* b_ih3 = (const float*)d_in[7];
    const float* b_hh3 = (const float*)d_in[8];
    float* out = (float*)d_out;

    lstm_seq_kernel<<<BATCH, 64, 0, stream>>>(
        input, W_ih1, W_hh1, b_ih1, b_hh1, W_ih3, W_hh3, b_ih3, b_hh3, out);
}